// Round 2
// baseline (52204.419 us; speedup 1.0000x reference)
//
#include <hip/hip_runtime.h>

#define N_NODES 50000
#define N_EDGES 400000
#define NCLS 4
#define HID 32
#define HI 36                        // HID + IN_DIM
#define ROWS_P (N_NODES * NCLS)      // 200000 per-plane (n,c) rows

// tanh(x) = 1 - 2/(exp(2x)+1); clamp avoids inf*0 NaN in the NR step.
__device__ __forceinline__ float fast_tanh(float x) {
    x = fminf(15.0f, fmaxf(-15.0f, x));
    float e = __expf(2.0f * x);
    float d = 1.0f + e;
    float r = __builtin_amdgcn_rcpf(d);
    r = r * (2.0f - d * r);   // one Newton step
    return 1.0f - 2.0f * r;
}

// Per plane: m[n][c][0:32] = tanh(x @ inW + inb), m[n][c][32:36] = x (same across c)
__global__ void k_init(const float* __restrict__ x, const float* __restrict__ W,
                       const float* __restrict__ b, float* __restrict__ m) {
    unsigned t = blockIdx.x * 256 + threadIdx.x;
    if (t >= N_NODES * HI) return;
    unsigned idx = t % HI;
    unsigned n   = t / HI;
    float x0 = x[n * 4 + 0], x1 = x[n * 4 + 1];
    float x2 = x[n * 4 + 2], x3 = x[n * 4 + 3];
    float val;
    if (idx < 32) {
        float a = b[idx];
        a += x0 * W[idx] + x1 * W[32 + idx] + x2 * W[64 + idx] + x3 * W[96 + idx];
        val = fast_tanh(a);
    } else {
        val = (idx == 32) ? x0 : (idx == 33) ? x1 : (idx == 34) ? x2 : x3;
    }
    float* dst = m + (size_t)n * (NCLS * HI) + idx;
    dst[0] = val; dst[HI] = val; dst[2 * HI] = val; dst[3 * HI] = val;
}

// out[row][o] = sum_k m[row][k] * W[(o/32)*36 + k][o%32], W pre-offset per plane.
// OW=64 (edge u|v, node p|q), OW=32 (node r -> acc init). Bias added downstream.
template <int OW>
__global__ void k_gemm36(const float* __restrict__ m, const float* __restrict__ W,
                         float* __restrict__ out) {
    unsigned g   = blockIdx.x * 256 + threadIdx.x;   // exact grid: ROWS_P*OW
    unsigned row = g / OW;
    unsigned o   = g - row * OW;
    const float4* m4 = reinterpret_cast<const float4*>(m + (size_t)row * HI);
    float mr[36];
#pragma unroll
    for (int i = 0; i < 9; ++i) {
        float4 v = m4[i];
        mr[4 * i] = v.x; mr[4 * i + 1] = v.y; mr[4 * i + 2] = v.z; mr[4 * i + 3] = v.w;
    }
    unsigned sub = o >> 5, oo = o & 31;
    const float* wc = W + (sub * 36) * 32 + oo;
    float a = 0.f;
#pragma unroll
    for (int k = 0; k < 36; ++k) a += mr[k] * wc[k * 32];
    out[(size_t)row * OW + o] = a;
}

// Per (e,c): s = tanh( sum_o tanh(u[col]+v[row]+b1)[o]*w2[o] + b2 ); softmax over c.
__global__ void k_edge(const int* __restrict__ rowI, const int* __restrict__ colI,
                       const float* __restrict__ uv, const float* __restrict__ b1,
                       const float* __restrict__ w2, const float* __restrict__ b2,
                       float* __restrict__ dst) {
    unsigned g = blockIdx.x * 256 + threadIdx.x;   // exact grid: E*4
    unsigned c = g & 3;
    unsigned e = g >> 2;
    int row = rowI[e];
    int col = colI[e];
    const float4* u4 = reinterpret_cast<const float4*>(uv + (((size_t)col * 4 + c) * 64));
    const float4* v4 = reinterpret_cast<const float4*>(uv + (((size_t)row * 4 + c) * 64) + 32);
    float t2 = b2[0];
#pragma unroll
    for (int i = 0; i < 8; ++i) {
        float4 uu = u4[i], vv = v4[i];
        t2 += fast_tanh(uu.x + vv.x + b1[4 * i + 0]) * w2[4 * i + 0];
        t2 += fast_tanh(uu.y + vv.y + b1[4 * i + 1]) * w2[4 * i + 1];
        t2 += fast_tanh(uu.z + vv.z + b1[4 * i + 2]) * w2[4 * i + 2];
        t2 += fast_tanh(uu.w + vv.w + b1[4 * i + 3]) * w2[4 * i + 3];
    }
    float s  = fast_tanh(t2);
    float m1 = fmaxf(s, __shfl_xor(s, 1, 4));
    float mx = fmaxf(m1, __shfl_xor(m1, 2, 4));
    float ex = __expf(s - mx);
    float sm = ex + __shfl_xor(ex, 1, 4);
    sm = sm + __shfl_xor(sm, 2, 4);
    dst[g] = ex / sm;
}

// acc[col,c,:] += ea * p[row,c,:];  acc[row,c,:] += ea * q[col,c,:]
// (acc pre-initialized with r = m@C by k_gemm36<32>)
__global__ void k_scatter(const int* __restrict__ rowI, const int* __restrict__ colI,
                          const float* __restrict__ ea, const float* __restrict__ pq,
                          float* __restrict__ acc) {
    unsigned g = blockIdx.x * 256 + threadIdx.x;   // exact grid: E*4
    unsigned c = g & 3;
    unsigned e = g >> 2;
    int row = rowI[e];
    int col = colI[e];
    float a = ea[g];
    const float4* p4 = reinterpret_cast<const float4*>(pq + (((size_t)row * 4 + c) * 64));
    const float4* q4 = reinterpret_cast<const float4*>(pq + (((size_t)col * 4 + c) * 64) + 32);
    float* aI = acc + ((size_t)col * 4 + c) * 32;
    float* aO = acc + ((size_t)row * 4 + c) * 32;
#pragma unroll
    for (int i = 0; i < 8; ++i) {
        float4 p = p4[i], q = q4[i];
        atomicAdd(&aI[4 * i + 0], a * p.x); atomicAdd(&aI[4 * i + 1], a * p.y);
        atomicAdd(&aI[4 * i + 2], a * p.z); atomicAdd(&aI[4 * i + 3], a * p.w);
        atomicAdd(&aO[4 * i + 0], a * q.x); atomicAdd(&aO[4 * i + 1], a * q.y);
        atomicAdd(&aO[4 * i + 2], a * q.z); atomicAdd(&aO[4 * i + 3], a * q.w);
    }
}

// t = tanh(acc + nb1) (r already folded into acc); H = tanh(t @ nW2 + nb2) -> m in place.
__global__ void k_node(const float* __restrict__ acc, const float* __restrict__ nb1,
                       const float* __restrict__ nW2, const float* __restrict__ nb2,
                       float* __restrict__ m) {
    __shared__ float w2[1024];
    __shared__ float tb[8 * 33];
    unsigned tid = threadIdx.x;
    for (unsigned idx = tid; idx < 1024; idx += 256) w2[idx] = nW2[idx];
    unsigned rl = tid >> 5, k = tid & 31;
    unsigned row = blockIdx.x * 8 + rl;
    float t = fast_tanh(acc[(size_t)row * 32 + k] + nb1[k]);
    tb[rl * 33 + k] = t;
    __syncthreads();
    float h = nb2[k];
#pragma unroll
    for (int kk = 0; kk < 32; ++kk) h += tb[rl * 33 + kk] * w2[kk * 32 + k];
    m[(size_t)row * HI + k] = fast_tanh(h);
}

extern "C" void kernel_launch(void* const* d_in, const int* in_sizes, int n_in,
                              void* d_out, int out_size, void* d_ws, size_t ws_size,
                              hipStream_t stream) {
    const float* x   = (const float*)d_in[0];
    const int*   ei  = (const int*)d_in[1];
    const float* inW = (const float*)d_in[2];
    const float* inb = (const float*)d_in[3];
    const float* eW1 = (const float*)d_in[4];
    const float* eb1 = (const float*)d_in[5];
    const float* eW2 = (const float*)d_in[6];
    const float* eb2 = (const float*)d_in[7];
    const float* nW1 = (const float*)d_in[8];
    const float* nb1 = (const float*)d_in[9];
    const float* nW2 = (const float*)d_in[10];
    const float* nb2 = (const float*)d_in[11];
    float* out = (float*)d_out;

    // Per-plane workspace (floats): m[7.2M] | pq/uv[12.8M] | ea[1.6M] | acc[6.4M] = 112 MB
    float* m   = (float*)d_ws;
    float* pq  = m  + (size_t)ROWS_P * HI;
    float* ea  = pq + (size_t)ROWS_P * 64;
    float* acc = ea + (size_t)N_EDGES * 4;

    for (int j = 0; j < 3; ++j) {
        const int*   rowI = ei + (size_t)j * 2 * N_EDGES;
        const int*   colI = rowI + N_EDGES;
        const float* eW1j = eW1 + j * 72 * 32;
        const float* eb1j = eb1 + j * 32;
        const float* eW2j = eW2 + j * 32;
        const float* eb2j = eb2 + j;
        const float* nW1j = nW1 + j * 108 * 32;
        const float* nb1j = nb1 + j * 32;
        const float* nW2j = nW2 + j * 1024;
        const float* nb2j = nb2 + j * 32;

        k_init<<<(N_NODES * HI + 255) / 256, 256, 0, stream>>>(
            x + (size_t)j * N_NODES * 4, inW + j * 128, inb + j * 32, m);

        for (int it = 0; it < 3; ++it) {
            k_gemm36<64><<<ROWS_P * 64 / 256, 256, 0, stream>>>(m, eW1j, pq);
            k_edge<<<N_EDGES * 4 / 256, 256, 0, stream>>>(rowI, colI, pq, eb1j, eW2j, eb2j, ea);
            k_gemm36<64><<<ROWS_P * 64 / 256, 256, 0, stream>>>(m, nW1j, pq);
            k_gemm36<32><<<ROWS_P * 32 / 256, 256, 0, stream>>>(m, nW1j + 72 * 32, acc);
            k_scatter<<<N_EDGES * 4 / 256, 256, 0, stream>>>(rowI, colI, ea, pq, acc);
            k_node<<<ROWS_P / 8, 256, 0, stream>>>(acc, nb1j, nW2j, nb2j, m);
        }
        k_gemm36<64><<<ROWS_P * 64 / 256, 256, 0, stream>>>(m, eW1j, pq);
        k_edge<<<N_EDGES * 4 / 256, 256, 0, stream>>>(rowI, colI, pq, eb1j, eW2j, eb2j,
                                                      out + (size_t)j * N_EDGES * 4);
    }
}

// Round 3
// 5595.235 us; speedup vs baseline: 9.3302x; 9.3302x over previous
//
#include <hip/hip_runtime.h>

#define N_NODES 50000
#define N_EDGES 400000
#define NCLS 4
#define HID 32
#define HI 36                        // HID + IN_DIM
#define ROWS_P (N_NODES * NCLS)      // 200000 per-plane (n,c) rows

// tanh(x) = 1 - 2/(exp(2x)+1); clamp avoids inf*0 NaN in the NR step.
__device__ __forceinline__ float fast_tanh(float x) {
    x = fminf(15.0f, fmaxf(-15.0f, x));
    float e = __expf(2.0f * x);
    float d = 1.0f + e;
    float r = __builtin_amdgcn_rcpf(d);
    r = r * (2.0f - d * r);   // one Newton step
    return 1.0f - 2.0f * r;
}

// Per plane: m[n][c][0:32] = tanh(x @ inW + inb), m[n][c][32:36] = x (same across c)
__global__ void k_init(const float* __restrict__ x, const float* __restrict__ W,
                       const float* __restrict__ b, float* __restrict__ m) {
    unsigned t = blockIdx.x * 256 + threadIdx.x;
    if (t >= N_NODES * HI) return;
    unsigned idx = t % HI;
    unsigned n   = t / HI;
    float x0 = x[n * 4 + 0], x1 = x[n * 4 + 1];
    float x2 = x[n * 4 + 2], x3 = x[n * 4 + 3];
    float val;
    if (idx < 32) {
        float a = b[idx];
        a += x0 * W[idx] + x1 * W[32 + idx] + x2 * W[64 + idx] + x3 * W[96 + idx];
        val = fast_tanh(a);
    } else {
        val = (idx == 32) ? x0 : (idx == 33) ? x1 : (idx == 34) ? x2 : x3;
    }
    float* dst = m + (size_t)n * (NCLS * HI) + idx;
    dst[0] = val; dst[HI] = val; dst[2 * HI] = val; dst[3 * HI] = val;
}

// ---------------- CSR build (per plane, once) ----------------
__global__ void k_hist(const int* __restrict__ rowI, const int* __restrict__ colI,
                       int* __restrict__ inCnt, int* __restrict__ outCnt) {
    unsigned e = blockIdx.x * 256 + threadIdx.x;
    if (e >= N_EDGES) return;
    atomicAdd(&inCnt[colI[e]], 1);
    atomicAdd(&outCnt[rowI[e]], 1);
}

// Exclusive scan of 50000 counts -> 50001 offsets. block 0: in, block 1: out.
__global__ void k_scan(const int* __restrict__ inCnt, const int* __restrict__ outCnt,
                       int* __restrict__ inOff, int* __restrict__ outOff) {
    const int* cnt = blockIdx.x ? outCnt : inCnt;
    int*       off = blockIdx.x ? outOff : inOff;
    __shared__ int sh[16];
    __shared__ int carry;
    int tid = threadIdx.x;            // 1024
    int lane = tid & 63, wid = tid >> 6;
    if (tid == 0) carry = 0;
    __syncthreads();
    for (int base = 0; base < N_NODES; base += 1024) {
        int i = base + tid;
        int v = (i < N_NODES) ? cnt[i] : 0;
        int val = v;
#pragma unroll
        for (int d = 1; d < 64; d <<= 1) {
            int t = __shfl_up(val, d, 64);
            if (lane >= d) val += t;
        }
        if (lane == 63) sh[wid] = val;
        __syncthreads();
        if (tid < 16) {
            int s = sh[tid];
#pragma unroll
            for (int d = 1; d < 16; d <<= 1) {
                int t = __shfl_up(s, d, 16);
                if (tid >= d) s += t;
            }
            sh[tid] = s;
        }
        __syncthreads();
        int waveOff = (wid == 0) ? 0 : sh[wid - 1];
        int incl = val + waveOff + carry;
        if (i < N_NODES) off[i] = incl - v;
        __syncthreads();
        if (tid == 1023) carry = incl;
        __syncthreads();
    }
    if (tid == 0) off[N_NODES] = carry;
}

// inList[n's slots] = (e, row(e)) for edges with col==n; outList: (e, col(e)) for row==n.
__global__ void k_fill(const int* __restrict__ rowI, const int* __restrict__ colI,
                       const int* __restrict__ inOff, const int* __restrict__ outOff,
                       int* __restrict__ inCur, int* __restrict__ outCur,
                       int2* __restrict__ inList, int2* __restrict__ outList) {
    unsigned e = blockIdx.x * 256 + threadIdx.x;
    if (e >= N_EDGES) return;
    int r = rowI[e], c = colI[e];
    int pi = inOff[c] + atomicAdd(&inCur[c], 1);
    inList[pi] = make_int2((int)e, r);
    int po = outOff[r] + atomicAdd(&outCur[r], 1);
    outList[po] = make_int2((int)e, c);
}

// ---------------- per-iteration kernels ----------------

// out[row][o] = sum_k m[row][k] * W[(o/32)*36 + k][o%32]; OW=64 (u|v or p|q).
template <int OW>
__global__ void k_gemm36(const float* __restrict__ m, const float* __restrict__ W,
                         float* __restrict__ out) {
    unsigned g   = blockIdx.x * 256 + threadIdx.x;   // exact grid: ROWS_P*OW
    unsigned row = g / OW;
    unsigned o   = g - row * OW;
    const float4* m4 = reinterpret_cast<const float4*>(m + (size_t)row * HI);
    float mr[36];
#pragma unroll
    for (int i = 0; i < 9; ++i) {
        float4 v = m4[i];
        mr[4 * i] = v.x; mr[4 * i + 1] = v.y; mr[4 * i + 2] = v.z; mr[4 * i + 3] = v.w;
    }
    unsigned sub = o >> 5, oo = o & 31;
    const float* wc = W + (sub * 36) * 32 + oo;
    float a = 0.f;
#pragma unroll
    for (int k = 0; k < 36; ++k) a += mr[k] * wc[k * 32];
    out[(size_t)row * OW + o] = a;
}

// Per (e,c): s = tanh( sum_o tanh(u[col]+v[row]+b1)[o]*w2[o] + b2 ); softmax over c.
__global__ void k_edge(const int* __restrict__ rowI, const int* __restrict__ colI,
                       const float* __restrict__ uv, const float* __restrict__ b1,
                       const float* __restrict__ w2, const float* __restrict__ b2,
                       float* __restrict__ dst) {
    unsigned g = blockIdx.x * 256 + threadIdx.x;   // exact grid: E*4
    unsigned c = g & 3;
    unsigned e = g >> 2;
    int row = rowI[e];
    int col = colI[e];
    const float4* u4 = reinterpret_cast<const float4*>(uv + (((size_t)col * 4 + c) * 64));
    const float4* v4 = reinterpret_cast<const float4*>(uv + (((size_t)row * 4 + c) * 64) + 32);
    float t2 = b2[0];
#pragma unroll
    for (int i = 0; i < 8; ++i) {
        float4 uu = u4[i], vv = v4[i];
        t2 += fast_tanh(uu.x + vv.x + b1[4 * i + 0]) * w2[4 * i + 0];
        t2 += fast_tanh(uu.y + vv.y + b1[4 * i + 1]) * w2[4 * i + 1];
        t2 += fast_tanh(uu.z + vv.z + b1[4 * i + 2]) * w2[4 * i + 2];
        t2 += fast_tanh(uu.w + vv.w + b1[4 * i + 3]) * w2[4 * i + 3];
    }
    float s  = fast_tanh(t2);
    float m1 = fmaxf(s, __shfl_xor(s, 1, 4));
    float mx = fmaxf(m1, __shfl_xor(m1, 2, 4));
    float ex = __expf(s - mx);
    float sm = ex + __shfl_xor(ex, 1, 4);
    sm = sm + __shfl_xor(sm, 2, 4);
    dst[g] = ex / sm;
}

// Fused node net: h = m[row]@C + nb1 + sum_in ea*p[partner] + sum_out ea*q[partner];
// t = tanh(h); H = tanh(t @ nW2 + nb2) -> m[row][0:32] in place. 8 rows x 32 lanes.
__global__ void k_node(float* __restrict__ m, const float* __restrict__ pq,
                       const float* __restrict__ ea,
                       const int* __restrict__ inOff, const int2* __restrict__ inList,
                       const int* __restrict__ outOff, const int2* __restrict__ outList,
                       const float* __restrict__ WC, const float* __restrict__ nb1,
                       const float* __restrict__ nW2, const float* __restrict__ nb2) {
    __shared__ float sC[36 * 32];
    __shared__ float sW2[32 * 32];
    __shared__ float tb[8 * 33];
    unsigned tid = threadIdx.x;
    for (unsigned i = tid; i < 36 * 32; i += 256) sC[i] = WC[i];
    for (unsigned i = tid; i < 32 * 32; i += 256) sW2[i] = nW2[i];
    unsigned rl = tid >> 5, k = tid & 31;
    unsigned row = blockIdx.x * 8 + rl;   // flat (n*4 + c)
    unsigned n = row >> 2, c = row & 3;
    const float4* m4 = reinterpret_cast<const float4*>(m + (size_t)row * HI);
    float mr[36];
#pragma unroll
    for (int i = 0; i < 9; ++i) {
        float4 v = m4[i];
        mr[4 * i] = v.x; mr[4 * i + 1] = v.y; mr[4 * i + 2] = v.z; mr[4 * i + 3] = v.w;
    }
    __syncthreads();
    float h = nb1[k];
#pragma unroll
    for (int kk = 0; kk < 36; ++kk) h += mr[kk] * sC[kk * 32 + k];
    int i0 = inOff[n], i1 = inOff[n + 1];
    for (int idx = i0; idx < i1; ++idx) {
        int2 ep = inList[idx];
        float a = ea[(size_t)ep.x * 4 + c];
        h += a * pq[(((size_t)ep.y * 4) + c) * 64 + k];
    }
    int o0 = outOff[n], o1 = outOff[n + 1];
    for (int idx = o0; idx < o1; ++idx) {
        int2 ep = outList[idx];
        float a = ea[(size_t)ep.x * 4 + c];
        h += a * pq[(((size_t)ep.y * 4) + c) * 64 + 32 + k];
    }
    float t = fast_tanh(h);
    tb[rl * 33 + k] = t;
    __syncthreads();
    float hh = nb2[k];
#pragma unroll
    for (int kk = 0; kk < 32; ++kk) hh += tb[rl * 33 + kk] * sW2[kk * 32 + k];
    m[(size_t)row * HI + k] = fast_tanh(hh);
}

extern "C" void kernel_launch(void* const* d_in, const int* in_sizes, int n_in,
                              void* d_out, int out_size, void* d_ws, size_t ws_size,
                              hipStream_t stream) {
    const float* x   = (const float*)d_in[0];
    const int*   ei  = (const int*)d_in[1];
    const float* inW = (const float*)d_in[2];
    const float* inb = (const float*)d_in[3];
    const float* eW1 = (const float*)d_in[4];
    const float* eb1 = (const float*)d_in[5];
    const float* eW2 = (const float*)d_in[6];
    const float* eb2 = (const float*)d_in[7];
    const float* nW1 = (const float*)d_in[8];
    const float* nb1 = (const float*)d_in[9];
    const float* nW2 = (const float*)d_in[10];
    const float* nb2 = (const float*)d_in[11];
    float* out = (float*)d_out;

    // Workspace: m 7.2M | pq/uv 12.8M | ea 1.6M floats, then CSR ints (~94 MB total)
    float* m    = (float*)d_ws;
    float* pq   = m  + (size_t)ROWS_P * HI;
    float* ea   = pq + (size_t)ROWS_P * 64;
    int*   inOff  = (int*)(ea + (size_t)N_EDGES * 4);
    int*   outOff = inOff + (N_NODES + 1);
    int*   inCnt  = outOff + (N_NODES + 1);   // also reused as cursors
    int*   outCnt = inCnt + N_NODES;
    int2*  inList  = (int2*)(outCnt + N_NODES + 2);  // +2 keeps 8B alignment
    int2*  outList = inList + N_EDGES;

    const int gridE = (N_EDGES + 255) / 256;

    for (int j = 0; j < 3; ++j) {
        const int*   rowI = ei + (size_t)j * 2 * N_EDGES;
        const int*   colI = rowI + N_EDGES;
        const float* eW1j = eW1 + j * 72 * 32;
        const float* eb1j = eb1 + j * 32;
        const float* eW2j = eW2 + j * 32;
        const float* eb2j = eb2 + j;
        const float* nW1j = nW1 + j * 108 * 32;
        const float* nb1j = nb1 + j * 32;
        const float* nW2j = nW2 + j * 1024;
        const float* nb2j = nb2 + j * 32;

        // CSR build
        hipMemsetAsync(inCnt, 0, 2 * N_NODES * sizeof(int), stream);
        k_hist<<<gridE, 256, 0, stream>>>(rowI, colI, inCnt, outCnt);
        k_scan<<<2, 1024, 0, stream>>>(inCnt, outCnt, inOff, outOff);
        hipMemsetAsync(inCnt, 0, 2 * N_NODES * sizeof(int), stream);
        k_fill<<<gridE, 256, 0, stream>>>(rowI, colI, inOff, outOff, inCnt, outCnt,
                                          inList, outList);

        k_init<<<(N_NODES * HI + 255) / 256, 256, 0, stream>>>(
            x + (size_t)j * N_NODES * 4, inW + j * 128, inb + j * 32, m);

        for (int it = 0; it < 3; ++it) {
            k_gemm36<64><<<ROWS_P * 64 / 256, 256, 0, stream>>>(m, eW1j, pq);
            k_edge<<<N_EDGES * 4 / 256, 256, 0, stream>>>(rowI, colI, pq, eb1j, eW2j, eb2j, ea);
            k_gemm36<64><<<ROWS_P * 64 / 256, 256, 0, stream>>>(m, nW1j, pq);
            k_node<<<ROWS_P / 8, 256, 0, stream>>>(m, pq, ea, inOff, inList, outOff, outList,
                                                   nW1j + 72 * 32, nb1j, nW2j, nb2j);
        }
        k_gemm36<64><<<ROWS_P * 64 / 256, 256, 0, stream>>>(m, eW1j, pq);
        k_edge<<<N_EDGES * 4 / 256, 256, 0, stream>>>(rowI, colI, pq, eb1j, eW2j, eb2j,
                                                      out + (size_t)j * N_EDGES * 4);
    }
}

// Round 4
// 5100.260 us; speedup vs baseline: 10.2356x; 1.0970x over previous
//
#include <hip/hip_runtime.h>

#define N_NODES 50000
#define N_EDGES 400000
#define NCLS 4
#define HID 32
#define HI 36                        // HID + IN_DIM
#define ROWS_P (N_NODES * NCLS)      // 200000 per-plane (n,c) rows

// tanh(x) = 1 - 2/(exp(2x)+1); clamp avoids inf*0 NaN in the NR step.
__device__ __forceinline__ float fast_tanh(float x) {
    x = fminf(15.0f, fmaxf(-15.0f, x));
    float e = __expf(2.0f * x);
    float d = 1.0f + e;
    float r = __builtin_amdgcn_rcpf(d);
    r = r * (2.0f - d * r);   // one Newton step
    return 1.0f - 2.0f * r;
}

// Per plane: m[n][c][0:32] = tanh(x @ inW + inb), m[n][c][32:36] = x (same across c)
__global__ void k_init(const float* __restrict__ x, const float* __restrict__ W,
                       const float* __restrict__ b, float* __restrict__ m) {
    unsigned t = blockIdx.x * 256 + threadIdx.x;
    if (t >= N_NODES * HI) return;
    unsigned idx = t % HI;
    unsigned n   = t / HI;
    float x0 = x[n * 4 + 0], x1 = x[n * 4 + 1];
    float x2 = x[n * 4 + 2], x3 = x[n * 4 + 3];
    float val;
    if (idx < 32) {
        float a = b[idx];
        a += x0 * W[idx] + x1 * W[32 + idx] + x2 * W[64 + idx] + x3 * W[96 + idx];
        val = fast_tanh(a);
    } else {
        val = (idx == 32) ? x0 : (idx == 33) ? x1 : (idx == 34) ? x2 : x3;
    }
    float* dst = m + (size_t)n * (NCLS * HI) + idx;
    dst[0] = val; dst[HI] = val; dst[2 * HI] = val; dst[3 * HI] = val;
}

// ---------------- CSR build (per plane, once) ----------------
__global__ void k_hist(const int* __restrict__ rowI, const int* __restrict__ colI,
                       int* __restrict__ inCnt, int* __restrict__ outCnt) {
    unsigned e = blockIdx.x * 256 + threadIdx.x;
    if (e >= N_EDGES) return;
    atomicAdd(&inCnt[colI[e]], 1);
    atomicAdd(&outCnt[rowI[e]], 1);
}

// Exclusive scan of 50000 counts -> 50001 offsets. block 0: in, block 1: out.
__global__ void k_scan(const int* __restrict__ inCnt, const int* __restrict__ outCnt,
                       int* __restrict__ inOff, int* __restrict__ outOff) {
    const int* cnt = blockIdx.x ? outCnt : inCnt;
    int*       off = blockIdx.x ? outOff : inOff;
    __shared__ int sh[16];
    __shared__ int carry;
    int tid = threadIdx.x;            // 1024
    int lane = tid & 63, wid = tid >> 6;
    if (tid == 0) carry = 0;
    __syncthreads();
    for (int base = 0; base < N_NODES; base += 1024) {
        int i = base + tid;
        int v = (i < N_NODES) ? cnt[i] : 0;
        int val = v;
#pragma unroll
        for (int d = 1; d < 64; d <<= 1) {
            int t = __shfl_up(val, d, 64);
            if (lane >= d) val += t;
        }
        if (lane == 63) sh[wid] = val;
        __syncthreads();
        if (tid < 16) {
            int s = sh[tid];
#pragma unroll
            for (int d = 1; d < 16; d <<= 1) {
                int t = __shfl_up(s, d, 16);
                if (tid >= d) s += t;
            }
            sh[tid] = s;
        }
        __syncthreads();
        int waveOff = (wid == 0) ? 0 : sh[wid - 1];
        int incl = val + waveOff + carry;
        if (i < N_NODES) off[i] = incl - v;
        __syncthreads();
        if (tid == 1023) carry = incl;
        __syncthreads();
    }
    if (tid == 0) off[N_NODES] = carry;
}

// inL[pi] = (e, row, col, posOut); outP[po] = col (partner for the out-gather).
__global__ void k_fill(const int* __restrict__ rowI, const int* __restrict__ colI,
                       const int* __restrict__ inOff, const int* __restrict__ outOff,
                       int* __restrict__ inCur, int* __restrict__ outCur,
                       int4* __restrict__ inL, int* __restrict__ outP) {
    unsigned e = blockIdx.x * 256 + threadIdx.x;
    if (e >= N_EDGES) return;
    int r = rowI[e], c = colI[e];
    int pi = inOff[c] + atomicAdd(&inCur[c], 1);
    int po = outOff[r] + atomicAdd(&outCur[r], 1);
    inL[pi] = make_int4((int)e, r, c, po);
    outP[po] = c;
}

// ---------------- per-iteration kernels ----------------

// Split-plane projection: out0[row][k] = m[row] @ W[0:36], out1[row][k] = m[row] @ W[36:72]
__global__ void k_gemm_uv(const float* __restrict__ m, const float* __restrict__ W,
                          float* __restrict__ out0, float* __restrict__ out1) {
    unsigned g   = blockIdx.x * 256 + threadIdx.x;   // exact grid: ROWS_P*64
    unsigned row = g >> 6;
    unsigned o   = g & 63;
    const float4* m4 = reinterpret_cast<const float4*>(m + (size_t)row * HI);
    float mr[36];
#pragma unroll
    for (int i = 0; i < 9; ++i) {
        float4 v = m4[i];
        mr[4 * i] = v.x; mr[4 * i + 1] = v.y; mr[4 * i + 2] = v.z; mr[4 * i + 3] = v.w;
    }
    unsigned sub = o >> 5, oo = o & 31;
    const float* wc = W + (sub * 36) * 32 + oo;
    float a = 0.f;
#pragma unroll
    for (int k = 0; k < 36; ++k) a += mr[k] * wc[k * 32];
    float* dst = sub ? out1 : out0;
    dst[(size_t)row * 32 + oo] = a;
}

// Edges in in-CSR order (grouped by col -> u side L1-resident).
// Per (idx,c): s = tanh(sum_o tanh(u[col]+v[row]+b1)*w2 + b2); softmax over c (4 lanes).
// Intermediate: write eaIn (coalesced) + eaOut (16B scatter). Final: write dst[e*4+c].
template <bool FINAL>
__global__ void k_edge(const int4* __restrict__ inL, const float* __restrict__ u,
                       const float* __restrict__ v, const float* __restrict__ b1,
                       const float* __restrict__ w2, const float* __restrict__ b2,
                       float* __restrict__ eaIn, float* __restrict__ eaOut,
                       float* __restrict__ dst) {
    unsigned g   = blockIdx.x * 256 + threadIdx.x;   // exact grid: E*4
    unsigned c   = g & 3;
    unsigned idx = g >> 2;
    int4 ent = inL[idx];   // (e, row, col, posOut)
    const float4* u4 = reinterpret_cast<const float4*>(u + ((size_t)ent.z * 4 + c) * 32);
    const float4* v4 = reinterpret_cast<const float4*>(v + ((size_t)ent.y * 4 + c) * 32);
    float t2 = b2[0];
#pragma unroll
    for (int i = 0; i < 8; ++i) {
        float4 uu = u4[i], vv = v4[i];
        t2 += fast_tanh(uu.x + vv.x + b1[4 * i + 0]) * w2[4 * i + 0];
        t2 += fast_tanh(uu.y + vv.y + b1[4 * i + 1]) * w2[4 * i + 1];
        t2 += fast_tanh(uu.z + vv.z + b1[4 * i + 2]) * w2[4 * i + 2];
        t2 += fast_tanh(uu.w + vv.w + b1[4 * i + 3]) * w2[4 * i + 3];
    }
    float s  = fast_tanh(t2);
    float m1 = fmaxf(s, __shfl_xor(s, 1, 4));
    float mx = fmaxf(m1, __shfl_xor(m1, 2, 4));
    float ex = __expf(s - mx);
    float sm = ex + __shfl_xor(ex, 1, 4);
    sm = sm + __shfl_xor(sm, 2, 4);
    float val = ex / sm;
    if (FINAL) {
        dst[(size_t)ent.x * 4 + c] = val;
    } else {
        eaIn[g] = val;
        eaOut[(size_t)ent.w * 4 + c] = val;
    }
}

// Fused node net: h = m@C + nb1 + sum_in eaIn*p[partner] + sum_out eaOut*q[partner];
// H = tanh(tanh(h) @ nW2 + nb2) -> m[row][0:32] in place. 8 rows x 32 lanes.
__global__ void k_node(float* __restrict__ m,
                       const float* __restrict__ p, const float* __restrict__ q,
                       const float* __restrict__ eaIn, const float* __restrict__ eaOut,
                       const int* __restrict__ inOff, const int4* __restrict__ inL,
                       const int* __restrict__ outOff, const int* __restrict__ outP,
                       const float* __restrict__ WC, const float* __restrict__ nb1,
                       const float* __restrict__ nW2, const float* __restrict__ nb2) {
    __shared__ float sC[36 * 32];
    __shared__ float sW2[32 * 32];
    __shared__ float tb[8 * 33];
    unsigned tid = threadIdx.x;
    for (unsigned i = tid; i < 36 * 32; i += 256) sC[i] = WC[i];
    for (unsigned i = tid; i < 32 * 32; i += 256) sW2[i] = nW2[i];
    unsigned rl = tid >> 5, k = tid & 31;
    unsigned row = blockIdx.x * 8 + rl;   // flat (n*4 + c)
    unsigned n = row >> 2, c = row & 3;
    const float4* m4 = reinterpret_cast<const float4*>(m + (size_t)row * HI);
    float mr[36];
#pragma unroll
    for (int i = 0; i < 9; ++i) {
        float4 v = m4[i];
        mr[4 * i] = v.x; mr[4 * i + 1] = v.y; mr[4 * i + 2] = v.z; mr[4 * i + 3] = v.w;
    }
    __syncthreads();
    float h = nb1[k];
#pragma unroll
    for (int kk = 0; kk < 36; ++kk) h += mr[kk] * sC[kk * 32 + k];
    int i0 = inOff[n], i1 = inOff[n + 1];
    for (int idx = i0; idx < i1; ++idx) {
        int partner = inL[idx].y;
        float a = eaIn[(size_t)idx * 4 + c];
        h += a * p[(((size_t)partner * 4) + c) * 32 + k];
    }
    int o0 = outOff[n], o1 = outOff[n + 1];
    for (int idx = o0; idx < o1; ++idx) {
        int partner = outP[idx];
        float a = eaOut[(size_t)idx * 4 + c];
        h += a * q[(((size_t)partner * 4) + c) * 32 + k];
    }
    float t = fast_tanh(h);
    tb[rl * 33 + k] = t;
    __syncthreads();
    float hh = nb2[k];
#pragma unroll
    for (int kk = 0; kk < 32; ++kk) hh += tb[rl * 33 + kk] * sW2[kk * 32 + k];
    m[(size_t)row * HI + k] = fast_tanh(hh);
}

extern "C" void kernel_launch(void* const* d_in, const int* in_sizes, int n_in,
                              void* d_out, int out_size, void* d_ws, size_t ws_size,
                              hipStream_t stream) {
    const float* x   = (const float*)d_in[0];
    const int*   ei  = (const int*)d_in[1];
    const float* inW = (const float*)d_in[2];
    const float* inb = (const float*)d_in[3];
    const float* eW1 = (const float*)d_in[4];
    const float* eb1 = (const float*)d_in[5];
    const float* eW2 = (const float*)d_in[6];
    const float* eb2 = (const float*)d_in[7];
    const float* nW1 = (const float*)d_in[8];
    const float* nb1 = (const float*)d_in[9];
    const float* nW2 = (const float*)d_in[10];
    const float* nb2 = (const float*)d_in[11];
    float* out = (float*)d_out;

    // Workspace (floats): m 7.2M | X 12.8M (u/p, v/q alias) | eaIn 1.6M | eaOut 1.6M
    // then ints: inL int4 1.6M-int | outP 0.4M | offsets/counts ~0.2M  => ~102 MB total
    float* m    = (float*)d_ws;
    float* u    = m + (size_t)ROWS_P * HI;            // also p
    float* v    = u + (size_t)ROWS_P * 32;            // also q
    float* eaIn = v + (size_t)ROWS_P * 32;
    float* eaOut= eaIn + (size_t)N_EDGES * 4;
    int4*  inL  = (int4*)(eaOut + (size_t)N_EDGES * 4);   // 16B aligned (all prior counts x4B %16==0)
    int*   outP = (int*)(inL + N_EDGES);
    int*   inOff  = outP + N_EDGES;
    int*   outOff = inOff + (N_NODES + 1);
    int*   inCnt  = outOff + (N_NODES + 1);
    int*   outCnt = inCnt + N_NODES;

    const int gridE = (N_EDGES + 255) / 256;

    for (int j = 0; j < 3; ++j) {
        const int*   rowI = ei + (size_t)j * 2 * N_EDGES;
        const int*   colI = rowI + N_EDGES;
        const float* eW1j = eW1 + j * 72 * 32;
        const float* eb1j = eb1 + j * 32;
        const float* eW2j = eW2 + j * 32;
        const float* eb2j = eb2 + j;
        const float* nW1j = nW1 + j * 108 * 32;
        const float* nb1j = nb1 + j * 32;
        const float* nW2j = nW2 + j * 1024;
        const float* nb2j = nb2 + j * 32;

        // CSR build
        hipMemsetAsync(inCnt, 0, 2 * N_NODES * sizeof(int), stream);
        k_hist<<<gridE, 256, 0, stream>>>(rowI, colI, inCnt, outCnt);
        k_scan<<<2, 1024, 0, stream>>>(inCnt, outCnt, inOff, outOff);
        hipMemsetAsync(inCnt, 0, 2 * N_NODES * sizeof(int), stream);
        k_fill<<<gridE, 256, 0, stream>>>(rowI, colI, inOff, outOff, inCnt, outCnt,
                                          inL, outP);

        k_init<<<(N_NODES * HI + 255) / 256, 256, 0, stream>>>(
            x + (size_t)j * N_NODES * 4, inW + j * 128, inb + j * 32, m);
        k_gemm_uv<<<ROWS_P * 64 / 256, 256, 0, stream>>>(m, eW1j, u, v);

        for (int it = 0; it < 3; ++it) {
            k_edge<false><<<N_EDGES * 4 / 256, 256, 0, stream>>>(
                inL, u, v, eb1j, eW2j, eb2j, eaIn, eaOut, nullptr);
            k_gemm_uv<<<ROWS_P * 64 / 256, 256, 0, stream>>>(m, nW1j, u, v);  // -> p,q
            k_node<<<ROWS_P / 8, 256, 0, stream>>>(m, u, v, eaIn, eaOut,
                                                   inOff, inL, outOff, outP,
                                                   nW1j + 72 * 32, nb1j, nW2j, nb2j);
            k_gemm_uv<<<ROWS_P * 64 / 256, 256, 0, stream>>>(m, eW1j, u, v);
        }
        k_edge<true><<<N_EDGES * 4 / 256, 256, 0, stream>>>(
            inL, u, v, eb1j, eW2j, eb2j, nullptr, nullptr, out + (size_t)j * N_EDGES * 4);
    }
}

// Round 5
// 4769.878 us; speedup vs baseline: 10.9446x; 1.0693x over previous
//
#include <hip/hip_runtime.h>
#include <hip/hip_fp16.h>

#define N_NODES 50000
#define N_EDGES 400000
#define NCLS 4
#define HID 32
#define HI 36                        // HID + IN_DIM
#define ROWS_P (N_NODES * NCLS)      // 200000 per-plane (n,c) rows

// tanh(x) = 1 - 2/(exp(2x)+1); clamp avoids inf*0 NaN in the NR step.
__device__ __forceinline__ float fast_tanh(float x) {
    x = fminf(15.0f, fmaxf(-15.0f, x));
    float e = __expf(2.0f * x);
    float d = 1.0f + e;
    float r = __builtin_amdgcn_rcpf(d);
    r = r * (2.0f - d * r);   // one Newton step
    return 1.0f - 2.0f * r;
}

union F4H8 { float4 f4; __half2 h2[4]; };

// Per plane: m[n][c][0:32] = tanh(x @ inW + inb), m[n][c][32:36] = x (same across c)
__global__ void k_init(const float* __restrict__ x, const float* __restrict__ W,
                       const float* __restrict__ b, float* __restrict__ m) {
    unsigned t = blockIdx.x * 256 + threadIdx.x;
    if (t >= N_NODES * HI) return;
    unsigned idx = t % HI;
    unsigned n   = t / HI;
    float x0 = x[n * 4 + 0], x1 = x[n * 4 + 1];
    float x2 = x[n * 4 + 2], x3 = x[n * 4 + 3];
    float val;
    if (idx < 32) {
        float a = b[idx];
        a += x0 * W[idx] + x1 * W[32 + idx] + x2 * W[64 + idx] + x3 * W[96 + idx];
        val = fast_tanh(a);
    } else {
        val = (idx == 32) ? x0 : (idx == 33) ? x1 : (idx == 34) ? x2 : x3;
    }
    float* dst = m + (size_t)n * (NCLS * HI) + idx;
    dst[0] = val; dst[HI] = val; dst[2 * HI] = val; dst[3 * HI] = val;
}

// ---------------- CSR build (per plane, once) ----------------
__global__ void k_hist(const int* __restrict__ rowI, const int* __restrict__ colI,
                       int* __restrict__ inCnt, int* __restrict__ outCnt) {
    unsigned e = blockIdx.x * 256 + threadIdx.x;
    if (e >= N_EDGES) return;
    atomicAdd(&inCnt[colI[e]], 1);
    atomicAdd(&outCnt[rowI[e]], 1);
}

// Exclusive scan of 50000 counts -> 50001 offsets. block 0: in, block 1: out.
__global__ void k_scan(const int* __restrict__ inCnt, const int* __restrict__ outCnt,
                       int* __restrict__ inOff, int* __restrict__ outOff) {
    const int* cnt = blockIdx.x ? outCnt : inCnt;
    int*       off = blockIdx.x ? outOff : inOff;
    __shared__ int sh[16];
    __shared__ int carry;
    int tid = threadIdx.x;            // 1024
    int lane = tid & 63, wid = tid >> 6;
    if (tid == 0) carry = 0;
    __syncthreads();
    for (int base = 0; base < N_NODES; base += 1024) {
        int i = base + tid;
        int v = (i < N_NODES) ? cnt[i] : 0;
        int val = v;
#pragma unroll
        for (int d = 1; d < 64; d <<= 1) {
            int t = __shfl_up(val, d, 64);
            if (lane >= d) val += t;
        }
        if (lane == 63) sh[wid] = val;
        __syncthreads();
        if (tid < 16) {
            int s = sh[tid];
#pragma unroll
            for (int d = 1; d < 16; d <<= 1) {
                int t = __shfl_up(s, d, 16);
                if (tid >= d) s += t;
            }
            sh[tid] = s;
        }
        __syncthreads();
        int waveOff = (wid == 0) ? 0 : sh[wid - 1];
        int incl = val + waveOff + carry;
        if (i < N_NODES) off[i] = incl - v;
        __syncthreads();
        if (tid == 1023) carry = incl;
        __syncthreads();
    }
    if (tid == 0) off[N_NODES] = carry;
}

// inL[pi]=(e,row,col,posOut); inP[pi]=row; outP[po]=col.
__global__ void k_fill(const int* __restrict__ rowI, const int* __restrict__ colI,
                       const int* __restrict__ inOff, const int* __restrict__ outOff,
                       int* __restrict__ inCur, int* __restrict__ outCur,
                       int4* __restrict__ inL, int* __restrict__ inP,
                       int* __restrict__ outP) {
    unsigned e = blockIdx.x * 256 + threadIdx.x;
    if (e >= N_EDGES) return;
    int r = rowI[e], c = colI[e];
    int pi = inOff[c] + atomicAdd(&inCur[c], 1);
    int po = outOff[r] + atomicAdd(&outCur[r], 1);
    inL[pi] = make_int4((int)e, r, c, po);
    inP[pi] = r;
    outP[po] = c;
}

// ---------------- per-iteration kernels ----------------

// Split-plane fp16 projection: out0[row][k] = m[row]@W[0:36], out1 = m[row]@W[36:72]
__global__ void k_gemm_uv(const float* __restrict__ m, const float* __restrict__ W,
                          __half* __restrict__ out0, __half* __restrict__ out1) {
    unsigned g   = blockIdx.x * 256 + threadIdx.x;   // exact grid: ROWS_P*64
    unsigned row = g >> 6;
    unsigned o   = g & 63;
    const float4* m4 = reinterpret_cast<const float4*>(m + (size_t)row * HI);
    float mr[36];
#pragma unroll
    for (int i = 0; i < 9; ++i) {
        float4 v = m4[i];
        mr[4 * i] = v.x; mr[4 * i + 1] = v.y; mr[4 * i + 2] = v.z; mr[4 * i + 3] = v.w;
    }
    unsigned sub = o >> 5, oo = o & 31;
    const float* wc = W + (sub * 36) * 32 + oo;
    float a = 0.f;
#pragma unroll
    for (int k = 0; k < 36; ++k) a += mr[k] * wc[k * 32];
    (sub ? out1 : out0)[(size_t)row * 32 + oo] = __float2half_rn(a);
}

// Edges in in-CSR order (grouped by col -> u side L1-resident).
// Per (idx,c): s = tanh(sum_o tanh(u[col]+v[row]+b1)*w2 + b2); softmax over c (4 lanes).
template <bool FINAL>
__global__ void k_edge(const int4* __restrict__ inL, const __half* __restrict__ u,
                       const __half* __restrict__ v, const float* __restrict__ b1,
                       const float* __restrict__ w2, const float* __restrict__ b2,
                       float* __restrict__ eaIn, float* __restrict__ eaOut,
                       float* __restrict__ dst) {
    unsigned g   = blockIdx.x * 256 + threadIdx.x;   // exact grid: E*4
    unsigned c   = g & 3;
    unsigned idx = g >> 2;
    int4 ent = inL[idx];   // (e, row, col, posOut)
    const float4* u4 = reinterpret_cast<const float4*>(u + ((size_t)ent.z * 4 + c) * 32);
    const float4* v4 = reinterpret_cast<const float4*>(v + ((size_t)ent.y * 4 + c) * 32);
    float t2 = b2[0];
#pragma unroll
    for (int i = 0; i < 4; ++i) {          // 4 x (16B = 8 halves)
        F4H8 U, V; U.f4 = u4[i]; V.f4 = v4[i];
#pragma unroll
        for (int jj = 0; jj < 4; ++jj) {
            float2 uf = __half22float2(U.h2[jj]);
            float2 vf = __half22float2(V.h2[jj]);
            int o = i * 8 + jj * 2;
            t2 += fast_tanh(uf.x + vf.x + b1[o])     * w2[o];
            t2 += fast_tanh(uf.y + vf.y + b1[o + 1]) * w2[o + 1];
        }
    }
    float s  = fast_tanh(t2);
    float m1 = fmaxf(s, __shfl_xor(s, 1, 4));
    float mx = fmaxf(m1, __shfl_xor(m1, 2, 4));
    float ex = __expf(s - mx);
    float sm = ex + __shfl_xor(ex, 1, 4);
    sm = sm + __shfl_xor(sm, 2, 4);
    float val = ex / sm;
    if (FINAL) {
        dst[(size_t)ent.x * 4 + c] = val;
    } else {
        eaIn[g] = val;
        eaOut[(size_t)ent.w * 4 + c] = val;
    }
}

// Fused node net: h = m@C + nb1 + sum_in eaIn*p[partner] + sum_out eaOut*q[partner];
// H = tanh(tanh(h) @ nW2 + nb2) -> m[row][0:32] in place. 8 rows x 32 lanes.
__global__ void k_node(float* __restrict__ m,
                       const __half* __restrict__ p, const __half* __restrict__ q,
                       const float* __restrict__ eaIn, const float* __restrict__ eaOut,
                       const int* __restrict__ inOff, const int* __restrict__ inP,
                       const int* __restrict__ outOff, const int* __restrict__ outP,
                       const float* __restrict__ WC, const float* __restrict__ nb1,
                       const float* __restrict__ nW2, const float* __restrict__ nb2) {
    __shared__ float sC[36 * 32];
    __shared__ float sW2[32 * 32];
    __shared__ float tb[8 * 33];
    unsigned tid = threadIdx.x;
    for (unsigned i = tid; i < 36 * 32; i += 256) sC[i] = WC[i];
    for (unsigned i = tid; i < 32 * 32; i += 256) sW2[i] = nW2[i];
    unsigned rl = tid >> 5, k = tid & 31;
    unsigned row = blockIdx.x * 8 + rl;   // flat (n*4 + c)
    unsigned n = row >> 2, c = row & 3;
    const float4* m4 = reinterpret_cast<const float4*>(m + (size_t)row * HI);
    float mr[36];
#pragma unroll
    for (int i = 0; i < 9; ++i) {
        float4 v = m4[i];
        mr[4 * i] = v.x; mr[4 * i + 1] = v.y; mr[4 * i + 2] = v.z; mr[4 * i + 3] = v.w;
    }
    __syncthreads();
    float h = nb1[k];
#pragma unroll
    for (int kk = 0; kk < 36; ++kk) h += mr[kk] * sC[kk * 32 + k];
    int i0 = inOff[n], i1 = inOff[n + 1];
    for (int idx = i0; idx < i1; ++idx) {
        int partner = inP[idx];
        float a = eaIn[(size_t)idx * 4 + c];
        h += a * __half2float(p[(((size_t)partner * 4) + c) * 32 + k]);
    }
    int o0 = outOff[n], o1 = outOff[n + 1];
    for (int idx = o0; idx < o1; ++idx) {
        int partner = outP[idx];
        float a = eaOut[(size_t)idx * 4 + c];
        h += a * __half2float(q[(((size_t)partner * 4) + c) * 32 + k]);
    }
    float t = fast_tanh(h);
    tb[rl * 33 + k] = t;
    __syncthreads();
    float hh = nb2[k];
#pragma unroll
    for (int kk = 0; kk < 32; ++kk) hh += tb[rl * 33 + kk] * sW2[kk * 32 + k];
    m[(size_t)row * HI + k] = fast_tanh(hh);
}

extern "C" void kernel_launch(void* const* d_in, const int* in_sizes, int n_in,
                              void* d_out, int out_size, void* d_ws, size_t ws_size,
                              hipStream_t stream) {
    const float* x   = (const float*)d_in[0];
    const int*   ei  = (const int*)d_in[1];
    const float* inW = (const float*)d_in[2];
    const float* inb = (const float*)d_in[3];
    const float* eW1 = (const float*)d_in[4];
    const float* eb1 = (const float*)d_in[5];
    const float* eW2 = (const float*)d_in[6];
    const float* eb2 = (const float*)d_in[7];
    const float* nW1 = (const float*)d_in[8];
    const float* nb1 = (const float*)d_in[9];
    const float* nW2 = (const float*)d_in[10];
    const float* nb2 = (const float*)d_in[11];
    float* out = (float*)d_out;

    // Workspace: m 28.8MB | u,v fp16 12.8MB ea | eaIn/eaOut 6.4MB ea | inL 6.4MB |
    // inP/outP 1.6MB ea | offsets/counts ~0.8MB  => ~78 MB total
    float*  m     = (float*)d_ws;
    __half* u     = (__half*)(m + (size_t)ROWS_P * HI);      // also p
    __half* v     = u + (size_t)ROWS_P * 32;                 // also q
    float*  eaIn  = (float*)(v + (size_t)ROWS_P * 32);
    float*  eaOut = eaIn + (size_t)N_EDGES * 4;
    int4*   inL   = (int4*)(eaOut + (size_t)N_EDGES * 4);
    int*    inP   = (int*)(inL + N_EDGES);
    int*    outP  = inP + N_EDGES;
    int*    inOff  = outP + N_EDGES;
    int*    outOff = inOff + (N_NODES + 1);
    int*    inCnt  = outOff + (N_NODES + 1);
    int*    outCnt = inCnt + N_NODES;

    const int gridE = (N_EDGES + 255) / 256;

    for (int j = 0; j < 3; ++j) {
        const int*   rowI = ei + (size_t)j * 2 * N_EDGES;
        const int*   colI = rowI + N_EDGES;
        const float* eW1j = eW1 + j * 72 * 32;
        const float* eb1j = eb1 + j * 32;
        const float* eW2j = eW2 + j * 32;
        const float* eb2j = eb2 + j;
        const float* nW1j = nW1 + j * 108 * 32;
        const float* nb1j = nb1 + j * 32;
        const float* nW2j = nW2 + j * 1024;
        const float* nb2j = nb2 + j * 32;

        // CSR build
        hipMemsetAsync(inCnt, 0, 2 * N_NODES * sizeof(int), stream);
        k_hist<<<gridE, 256, 0, stream>>>(rowI, colI, inCnt, outCnt);
        k_scan<<<2, 1024, 0, stream>>>(inCnt, outCnt, inOff, outOff);
        hipMemsetAsync(inCnt, 0, 2 * N_NODES * sizeof(int), stream);
        k_fill<<<gridE, 256, 0, stream>>>(rowI, colI, inOff, outOff, inCnt, outCnt,
                                          inL, inP, outP);

        k_init<<<(N_NODES * HI + 255) / 256, 256, 0, stream>>>(
            x + (size_t)j * N_NODES * 4, inW + j * 128, inb + j * 32, m);
        k_gemm_uv<<<ROWS_P * 64 / 256, 256, 0, stream>>>(m, eW1j, u, v);

        for (int it = 0; it < 3; ++it) {
            k_edge<false><<<N_EDGES * 4 / 256, 256, 0, stream>>>(
                inL, u, v, eb1j, eW2j, eb2j, eaIn, eaOut, nullptr);
            k_gemm_uv<<<ROWS_P * 64 / 256, 256, 0, stream>>>(m, nW1j, u, v);  // -> p,q
            k_node<<<ROWS_P / 8, 256, 0, stream>>>(m, u, v, eaIn, eaOut,
                                                   inOff, inP, outOff, outP,
                                                   nW1j + 72 * 32, nb1j, nW2j, nb2j);
            k_gemm_uv<<<ROWS_P * 64 / 256, 256, 0, stream>>>(m, eW1j, u, v);
        }
        k_edge<true><<<N_EDGES * 4 / 256, 256, 0, stream>>>(
            inL, u, v, eb1j, eW2j, eb2j, nullptr, nullptr, out + (size_t)j * N_EDGES * 4);
    }
}

// Round 6
// 3653.270 us; speedup vs baseline: 14.2898x; 1.3056x over previous
//
#include <hip/hip_runtime.h>
#include <hip/hip_fp16.h>

#define N_NODES 50000
#define N_EDGES 400000
#define NCLS 4
#define HID 32
#define HI 36                        // HID + IN_DIM
#define ROWS_P (N_NODES * NCLS)      // 200000 per-plane (n,c) rows

// tanh(x) = 1 - 2/(exp(2x)+1); clamp avoids inf*0 NaN in the NR step.
__device__ __forceinline__ float fast_tanh(float x) {
    x = fminf(15.0f, fmaxf(-15.0f, x));
    float e = __expf(2.0f * x);
    float d = 1.0f + e;
    float r = __builtin_amdgcn_rcpf(d);
    r = r * (2.0f - d * r);   // one Newton step
    return 1.0f - 2.0f * r;
}

union F4H8 { float4 f4; __half2 h2[4]; };

// Per plane: m[n][c][0:32] = tanh(x @ inW + inb), m[n][c][32:36] = x (same across c)
__global__ void k_init(const float* __restrict__ x, const float* __restrict__ W,
                       const float* __restrict__ b, float* __restrict__ m) {
    unsigned t = blockIdx.x * 256 + threadIdx.x;
    if (t >= N_NODES * HI) return;
    unsigned idx = t % HI;
    unsigned n   = t / HI;
    float x0 = x[n * 4 + 0], x1 = x[n * 4 + 1];
    float x2 = x[n * 4 + 2], x3 = x[n * 4 + 3];
    float val;
    if (idx < 32) {
        float a = b[idx];
        a += x0 * W[idx] + x1 * W[32 + idx] + x2 * W[64 + idx] + x3 * W[96 + idx];
        val = fast_tanh(a);
    } else {
        val = (idx == 32) ? x0 : (idx == 33) ? x1 : (idx == 34) ? x2 : x3;
    }
    float* dst = m + (size_t)n * (NCLS * HI) + idx;
    dst[0] = val; dst[HI] = val; dst[2 * HI] = val; dst[3 * HI] = val;
}

// ---------------- CSR build (per plane, once) ----------------
__global__ void k_hist(const int* __restrict__ rowI, const int* __restrict__ colI,
                       int* __restrict__ inCnt, int* __restrict__ outCnt) {
    unsigned e = blockIdx.x * 256 + threadIdx.x;
    if (e >= N_EDGES) return;
    atomicAdd(&inCnt[colI[e]], 1);
    atomicAdd(&outCnt[rowI[e]], 1);
}

// Exclusive scan of 50000 counts -> 50001 offsets. block 0: in, block 1: out.
__global__ void k_scan(const int* __restrict__ inCnt, const int* __restrict__ outCnt,
                       int* __restrict__ inOff, int* __restrict__ outOff) {
    const int* cnt = blockIdx.x ? outCnt : inCnt;
    int*       off = blockIdx.x ? outOff : inOff;
    __shared__ int sh[16];
    __shared__ int carry;
    int tid = threadIdx.x;            // 1024
    int lane = tid & 63, wid = tid >> 6;
    if (tid == 0) carry = 0;
    __syncthreads();
    for (int base = 0; base < N_NODES; base += 1024) {
        int i = base + tid;
        int v = (i < N_NODES) ? cnt[i] : 0;
        int val = v;
#pragma unroll
        for (int d = 1; d < 64; d <<= 1) {
            int t = __shfl_up(val, d, 64);
            if (lane >= d) val += t;
        }
        if (lane == 63) sh[wid] = val;
        __syncthreads();
        if (tid < 16) {
            int s = sh[tid];
#pragma unroll
            for (int d = 1; d < 16; d <<= 1) {
                int t = __shfl_up(s, d, 16);
                if (tid >= d) s += t;
            }
            sh[tid] = s;
        }
        __syncthreads();
        int waveOff = (wid == 0) ? 0 : sh[wid - 1];
        int incl = val + waveOff + carry;
        if (i < N_NODES) off[i] = incl - v;
        __syncthreads();
        if (tid == 1023) carry = incl;
        __syncthreads();
    }
    if (tid == 0) off[N_NODES] = carry;
}

// inL[pi]=(e,row,col,posOut); inP[pi]=row; outP[po]=col.
__global__ void k_fill(const int* __restrict__ rowI, const int* __restrict__ colI,
                       const int* __restrict__ inOff, const int* __restrict__ outOff,
                       int* __restrict__ inCur, int* __restrict__ outCur,
                       int4* __restrict__ inL, int* __restrict__ inP,
                       int* __restrict__ outP) {
    unsigned e = blockIdx.x * 256 + threadIdx.x;
    if (e >= N_EDGES) return;
    int r = rowI[e], c = colI[e];
    int pi = inOff[c] + atomicAdd(&inCur[c], 1);
    int po = outOff[r] + atomicAdd(&outCur[r], 1);
    inL[pi] = make_int4((int)e, r, c, po);
    inP[pi] = r;
    outP[po] = c;
}

// ---------------- per-iteration kernels ----------------

// Split-plane fp16 projection, 2 rows per thread (shares W loads across rows).
// out0[row][oo] = m[row]@W[0:36] col oo; out1: W[36:72].
__global__ void k_gemm_uv(const float* __restrict__ m, const float* __restrict__ W,
                          __half* __restrict__ out0, __half* __restrict__ out1) {
    unsigned g  = blockIdx.x * 256 + threadIdx.x;   // exact grid: (ROWS_P/2)*64
    unsigned pr = g >> 6;
    unsigned o  = g & 63;
    unsigned r0 = pr * 2;
    const float4* m40 = reinterpret_cast<const float4*>(m + (size_t)r0 * HI);
    const float4* m41 = reinterpret_cast<const float4*>(m + (size_t)(r0 + 1) * HI);
    float mr0[36], mr1[36];
#pragma unroll
    for (int i = 0; i < 9; ++i) {
        float4 a = m40[i], b = m41[i];
        mr0[4 * i] = a.x; mr0[4 * i + 1] = a.y; mr0[4 * i + 2] = a.z; mr0[4 * i + 3] = a.w;
        mr1[4 * i] = b.x; mr1[4 * i + 1] = b.y; mr1[4 * i + 2] = b.z; mr1[4 * i + 3] = b.w;
    }
    unsigned sub = o >> 5, oo = o & 31;
    const float* wc = W + (sub * 36) * 32 + oo;
    float a0 = 0.f, a1 = 0.f;
#pragma unroll
    for (int k = 0; k < 36; ++k) {
        float w = wc[k * 32];
        a0 += mr0[k] * w;
        a1 += mr1[k] * w;
    }
    __half* dst = sub ? out1 : out0;
    dst[(size_t)r0 * 32 + oo]       = __float2half_rn(a0);
    dst[(size_t)(r0 + 1) * 32 + oo] = __float2half_rn(a1);
}

// Edges in in-CSR order (grouped by col -> u side L1-resident).
// Per (idx,c): s = tanh(sum_o tanh(u[col]+v[row]+b1)*w2 + b2); softmax over c (4 lanes).
template <bool FINAL>
__global__ void k_edge(const int4* __restrict__ inL, const __half* __restrict__ u,
                       const __half* __restrict__ v, const float* __restrict__ b1,
                       const float* __restrict__ w2, const float* __restrict__ b2,
                       float* __restrict__ eaIn, float* __restrict__ eaOut,
                       float* __restrict__ dst) {
    unsigned g   = blockIdx.x * 256 + threadIdx.x;   // exact grid: E*4
    unsigned c   = g & 3;
    unsigned idx = g >> 2;
    int4 ent = inL[idx];   // (e, row, col, posOut)
    const float4* u4 = reinterpret_cast<const float4*>(u + ((size_t)ent.z * 4 + c) * 32);
    const float4* v4 = reinterpret_cast<const float4*>(v + ((size_t)ent.y * 4 + c) * 32);
    float t2 = b2[0];
#pragma unroll
    for (int i = 0; i < 4; ++i) {          // 4 x (16B = 8 halves)
        F4H8 U, V; U.f4 = u4[i]; V.f4 = v4[i];
#pragma unroll
        for (int jj = 0; jj < 4; ++jj) {
            float2 uf = __half22float2(U.h2[jj]);
            float2 vf = __half22float2(V.h2[jj]);
            int o = i * 8 + jj * 2;
            t2 += fast_tanh(uf.x + vf.x + b1[o])     * w2[o];
            t2 += fast_tanh(uf.y + vf.y + b1[o + 1]) * w2[o + 1];
        }
    }
    float s  = fast_tanh(t2);
    float m1 = fmaxf(s, __shfl_xor(s, 1, 4));
    float mx = fmaxf(m1, __shfl_xor(m1, 2, 4));
    float ex = __expf(s - mx);
    float sm = ex + __shfl_xor(ex, 1, 4);
    sm = sm + __shfl_xor(sm, 2, 4);
    float val = ex / sm;
    if (FINAL) {
        dst[(size_t)ent.x * 4 + c] = val;
    } else {
        eaIn[g] = val;
        eaOut[(size_t)ent.w * 4 + c] = val;
    }
}

// Fused node net with batched high-MLP gathers.
// h = m@C + nb1 + sum_in eaIn*p[partner] + sum_out eaOut*q[partner];
// H = tanh(tanh(h) @ nW2 + nb2) -> m[row][0:32] in place. 8 rows x 32 lanes.
__global__ void k_node(float* __restrict__ m,
                       const __half* __restrict__ p, const __half* __restrict__ q,
                       const float* __restrict__ eaIn, const float* __restrict__ eaOut,
                       const int* __restrict__ inOff, const int* __restrict__ inP,
                       const int* __restrict__ outOff, const int* __restrict__ outP,
                       const float* __restrict__ WC, const float* __restrict__ nb1,
                       const float* __restrict__ nW2, const float* __restrict__ nb2) {
    __shared__ float sC[36 * 32];
    __shared__ float sW2[32 * 32];
    __shared__ float tb[8 * 33];
    unsigned tid = threadIdx.x;
    for (unsigned i = tid; i < 36 * 32; i += 256) sC[i] = WC[i];
    for (unsigned i = tid; i < 32 * 32; i += 256) sW2[i] = nW2[i];
    unsigned rl = tid >> 5, k = tid & 31;
    unsigned row = blockIdx.x * 8 + rl;   // flat (n*4 + c)
    unsigned n = row >> 2, c = row & 3;
    const float4* m4 = reinterpret_cast<const float4*>(m + (size_t)row * HI);
    float mr[36];
#pragma unroll
    for (int i = 0; i < 9; ++i) {
        float4 v = m4[i];
        mr[4 * i] = v.x; mr[4 * i + 1] = v.y; mr[4 * i + 2] = v.z; mr[4 * i + 3] = v.w;
    }
    __syncthreads();
    float h = nb1[k];
#pragma unroll
    for (int kk = 0; kk < 36; ++kk) h += mr[kk] * sC[kk * 32 + k];

    // in-gather: batches of 16 independent loads (addresses uniform across the
    // 32-lane group -> L1 broadcast; invalid slots alias slot i0 with a=0).
    {
        int i0 = inOff[n], i1 = inOff[n + 1];
        for (int base = i0; base < i1; base += 16) {
            int prt[16]; float av[16];
#pragma unroll
            for (int kk = 0; kk < 16; ++kk) {
                int off = base + kk;
                bool ok = off < i1;
                int sa = ok ? off : i0;
                prt[kk] = inP[sa];
                av[kk]  = ok ? eaIn[(size_t)sa * 4 + c] : 0.f;
            }
#pragma unroll
            for (int kk = 0; kk < 16; ++kk)
                h += av[kk] * __half2float(p[(((size_t)prt[kk] * 4) + c) * 32 + k]);
        }
    }
    // out-gather
    {
        int o0 = outOff[n], o1 = outOff[n + 1];
        for (int base = o0; base < o1; base += 16) {
            int prt[16]; float av[16];
#pragma unroll
            for (int kk = 0; kk < 16; ++kk) {
                int off = base + kk;
                bool ok = off < o1;
                int sa = ok ? off : o0;
                prt[kk] = outP[sa];
                av[kk]  = ok ? eaOut[(size_t)sa * 4 + c] : 0.f;
            }
#pragma unroll
            for (int kk = 0; kk < 16; ++kk)
                h += av[kk] * __half2float(q[(((size_t)prt[kk] * 4) + c) * 32 + k]);
        }
    }
    float t = fast_tanh(h);
    tb[rl * 33 + k] = t;
    __syncthreads();
    float hh = nb2[k];
#pragma unroll
    for (int kk = 0; kk < 32; ++kk) hh += tb[rl * 33 + kk] * sW2[kk * 32 + k];
    m[(size_t)row * HI + k] = fast_tanh(hh);
}

extern "C" void kernel_launch(void* const* d_in, const int* in_sizes, int n_in,
                              void* d_out, int out_size, void* d_ws, size_t ws_size,
                              hipStream_t stream) {
    const float* x   = (const float*)d_in[0];
    const int*   ei  = (const int*)d_in[1];
    const float* inW = (const float*)d_in[2];
    const float* inb = (const float*)d_in[3];
    const float* eW1 = (const float*)d_in[4];
    const float* eb1 = (const float*)d_in[5];
    const float* eW2 = (const float*)d_in[6];
    const float* eb2 = (const float*)d_in[7];
    const float* nW1 = (const float*)d_in[8];
    const float* nb1 = (const float*)d_in[9];
    const float* nW2 = (const float*)d_in[10];
    const float* nb2 = (const float*)d_in[11];
    float* out = (float*)d_out;

    // Workspace: m 28.8MB | u,v fp16 12.8MB ea | eaIn/eaOut 6.4MB ea | inL 6.4MB |
    // inP/outP 1.6MB ea | offsets/counts ~0.8MB  => ~78 MB total
    float*  m     = (float*)d_ws;
    __half* u     = (__half*)(m + (size_t)ROWS_P * HI);      // also p
    __half* v     = u + (size_t)ROWS_P * 32;                 // also q
    float*  eaIn  = (float*)(v + (size_t)ROWS_P * 32);
    float*  eaOut = eaIn + (size_t)N_EDGES * 4;
    int4*   inL   = (int4*)(eaOut + (size_t)N_EDGES * 4);
    int*    inP   = (int*)(inL + N_EDGES);
    int*    outP  = inP + N_EDGES;
    int*    inOff  = outP + N_EDGES;
    int*    outOff = inOff + (N_NODES + 1);
    int*    inCnt  = outOff + (N_NODES + 1);
    int*    outCnt = inCnt + N_NODES;

    const int gridE = (N_EDGES + 255) / 256;

    for (int j = 0; j < 3; ++j) {
        const int*   rowI = ei + (size_t)j * 2 * N_EDGES;
        const int*   colI = rowI + N_EDGES;
        const float* eW1j = eW1 + j * 72 * 32;
        const float* eb1j = eb1 + j * 32;
        const float* eW2j = eW2 + j * 32;
        const float* eb2j = eb2 + j;
        const float* nW1j = nW1 + j * 108 * 32;
        const float* nb1j = nb1 + j * 32;
        const float* nW2j = nW2 + j * 1024;
        const float* nb2j = nb2 + j * 32;

        // CSR build
        hipMemsetAsync(inCnt, 0, 2 * N_NODES * sizeof(int), stream);
        k_hist<<<gridE, 256, 0, stream>>>(rowI, colI, inCnt, outCnt);
        k_scan<<<2, 1024, 0, stream>>>(inCnt, outCnt, inOff, outOff);
        hipMemsetAsync(inCnt, 0, 2 * N_NODES * sizeof(int), stream);
        k_fill<<<gridE, 256, 0, stream>>>(rowI, colI, inOff, outOff, inCnt, outCnt,
                                          inL, inP, outP);

        k_init<<<(N_NODES * HI + 255) / 256, 256, 0, stream>>>(
            x + (size_t)j * N_NODES * 4, inW + j * 128, inb + j * 32, m);
        k_gemm_uv<<<(ROWS_P / 2) * 64 / 256, 256, 0, stream>>>(m, eW1j, u, v);

        for (int it = 0; it < 3; ++it) {
            k_edge<false><<<N_EDGES * 4 / 256, 256, 0, stream>>>(
                inL, u, v, eb1j, eW2j, eb2j, eaIn, eaOut, nullptr);
            k_gemm_uv<<<(ROWS_P / 2) * 64 / 256, 256, 0, stream>>>(m, nW1j, u, v);  // -> p,q
            k_node<<<ROWS_P / 8, 256, 0, stream>>>(m, u, v, eaIn, eaOut,
                                                   inOff, inP, outOff, outP,
                                                   nW1j + 72 * 32, nb1j, nW2j, nb2j);
            k_gemm_uv<<<(ROWS_P / 2) * 64 / 256, 256, 0, stream>>>(m, eW1j, u, v);
        }
        k_edge<true><<<N_EDGES * 4 / 256, 256, 0, stream>>>(
            inL, u, v, eb1j, eW2j, eb2j, nullptr, nullptr, out + (size_t)j * N_EDGES * 4);
    }
}